// Round 12
// baseline (40.394 us; speedup 1.0000x reference)
//
#include <hip/hip_runtime.h>
#include <hip/hip_bf16.h>

#define EMB 16
#define HID 64
#define NE  8
#define TPG 64   // tokens per wave-group

typedef float  f32x4 __attribute__((ext_vector_type(4)));
typedef double f64x4 __attribute__((ext_vector_type(4)));
typedef short  s16x4 __attribute__((ext_vector_type(4)));

// fp32 -> bf16 via the standard HIP cast (RNE).
__device__ __forceinline__ short f2bf(float f) {
    union { __hip_bfloat16 h; short s; } u;
    u.h = __float2bfloat16(f);
    return u.s;
}
__device__ __forceinline__ s16x4 pack_bf16x4(float a, float b, float c, float d) {
    s16x4 r;
    r[0] = f2bf(a); r[1] = f2bf(b); r[2] = f2bf(c); r[3] = f2bf(d);
    return r;
}

__device__ __forceinline__ f32x4 vfmaf(float s, f32x4 a, f32x4 c) {
    f32x4 r;
    r[0] = fmaf(s, a[0], c[0]); r[1] = fmaf(s, a[1], c[1]);
    r[2] = fmaf(s, a[2], c[2]); r[3] = fmaf(s, a[3], c[3]);
    return r;
}
__device__ __forceinline__ f64x4 vfmad(double s, f32x4 a, f64x4 c) {
    f64x4 r;
    r[0] = fma(s, (double)a[0], c[0]); r[1] = fma(s, (double)a[1], c[1]);
    r[2] = fma(s, (double)a[2], c[2]); r[3] = fma(s, (double)a[3], c[3]);
    return r;
}

// ============================================================================
// Kernel 1: router (byte-identical to round 7 — proven spill-clean).
// ============================================================================
__global__ __launch_bounds__(256, 2)
void router_k(const float* __restrict__ x, const float* __restrict__ Wr,
              const float* __restrict__ br, float* __restrict__ gates,
              int n_tokens)
{
    __shared__ float wr_lds[EMB * NE];
    __shared__ float br_lds[NE];
    const int tid = threadIdx.x;
    if (tid < EMB * NE) wr_lds[tid] = Wr[tid];
    if (tid < NE) br_lds[tid] = br[tid];
    __syncthreads();

    const int t = blockIdx.x * 256 + tid;
    if (t >= n_tokens) return;

    const f32x4* xp = (const f32x4*)(x + (size_t)t * EMB);
    const f32x4 x0 = xp[0], x1 = xp[1], x2 = xp[2], x3 = xp[3];

    f32x4 lgA = *(const f32x4*)(br_lds + 0);
    f32x4 lgB = *(const f32x4*)(br_lds + 4);
#define RSTEP(K, XV) do { const float xv_ = (XV); \
        lgA = vfmaf(xv_, *(const f32x4*)(wr_lds + (K) * NE),     lgA); \
        lgB = vfmaf(xv_, *(const f32x4*)(wr_lds + (K) * NE + 4), lgB); } while (0)
    RSTEP(0,  x0[0]); RSTEP(1,  x0[1]); RSTEP(2,  x0[2]); RSTEP(3,  x0[3]);
    RSTEP(4,  x1[0]); RSTEP(5,  x1[1]); RSTEP(6,  x1[2]); RSTEP(7,  x1[3]);
    RSTEP(8,  x2[0]); RSTEP(9,  x2[1]); RSTEP(10, x2[2]); RSTEP(11, x2[3]);
    RSTEP(12, x3[0]); RSTEP(13, x3[1]); RSTEP(14, x3[2]); RSTEP(15, x3[3]);
#undef RSTEP

    float m1 = -1e30f, m2 = -1e30f, m3 = -1e30f;
#define MSCAN(V) do { const float v_ = (V); \
        const float hi_ = fmaxf(m1, v_), lo_ = fminf(m1, v_); \
        const float hi2_ = fmaxf(m2, lo_), lo2_ = fminf(m2, lo_); \
        m1 = hi_; m2 = hi2_; m3 = fmaxf(m3, lo2_); } while (0)
    MSCAN(lgA[0]); MSCAN(lgA[1]); MSCAN(lgA[2]); MSCAN(lgA[3]);
    MSCAN(lgB[0]); MSCAN(lgB[1]); MSCAN(lgB[2]); MSCAN(lgB[3]);
#undef MSCAN

    int sm = 0;
    sm |= (lgA[0] >= m2) << 0; sm |= (lgA[1] >= m2) << 1;
    sm |= (lgA[2] >= m2) << 2; sm |= (lgA[3] >= m2) << 3;
    sm |= (lgB[0] >= m2) << 4; sm |= (lgB[1] >= m2) << 5;
    sm |= (lgB[2] >= m2) << 6; sm |= (lgB[3] >= m2) << 7;

    if (__any(m2 - m3 < 1e-4f)) {
        f64x4 dA, dB;
        dA[0] = (double)br_lds[0]; dA[1] = (double)br_lds[1];
        dA[2] = (double)br_lds[2]; dA[3] = (double)br_lds[3];
        dB[0] = (double)br_lds[4]; dB[1] = (double)br_lds[5];
        dB[2] = (double)br_lds[6]; dB[3] = (double)br_lds[7];
#define DSTEP(K, XV) do { const double xv_ = (double)(XV); \
        dA = vfmad(xv_, *(const f32x4*)(wr_lds + (K) * NE),     dA); \
        dB = vfmad(xv_, *(const f32x4*)(wr_lds + (K) * NE + 4), dB); } while (0)
        DSTEP(0,  x0[0]); DSTEP(1,  x0[1]); DSTEP(2,  x0[2]); DSTEP(3,  x0[3]);
        DSTEP(4,  x1[0]); DSTEP(5,  x1[1]); DSTEP(6,  x1[2]); DSTEP(7,  x1[3]);
        DSTEP(8,  x2[0]); DSTEP(9,  x2[1]); DSTEP(10, x2[2]); DSTEP(11, x2[3]);
        DSTEP(12, x3[0]); DSTEP(13, x3[1]); DSTEP(14, x3[2]); DSTEP(15, x3[3]);
#undef DSTEP
        double M1 = -1e300, M2 = -1e300;
#define DSCAN(V) do { const double v_ = (V); \
        const double hi_ = fmax(M1, v_); M2 = fmax(M2, fmin(M1, v_)); M1 = hi_; } while (0)
        DSCAN(dA[0]); DSCAN(dA[1]); DSCAN(dA[2]); DSCAN(dA[3]);
        DSCAN(dB[0]); DSCAN(dB[1]); DSCAN(dB[2]); DSCAN(dB[3]);
#undef DSCAN
        sm = 0;
        sm |= (dA[0] >= M2) << 0; sm |= (dA[1] >= M2) << 1;
        sm |= (dA[2] >= M2) << 2; sm |= (dA[3] >= M2) << 3;
        sm |= (dB[0] >= M2) << 4; sm |= (dB[1] >= M2) << 5;
        sm |= (dB[2] >= M2) << 6; sm |= (dB[3] >= M2) << 7;
    }

    const float e0 = __expf(lgA[0] - m1), e1 = __expf(lgA[1] - m1);
    const float e2 = __expf(lgA[2] - m1), e3 = __expf(lgA[3] - m1);
    const float e4 = __expf(lgB[0] - m1), e5 = __expf(lgB[1] - m1);
    const float e6 = __expf(lgB[2] - m1), e7 = __expf(lgB[3] - m1);
    const float inv = 1.0f / (e0 + e1 + e2 + e3 + e4 + e5 + e6 + e7);
    f32x4 gA, gB;
    gA[0] = (sm & 1)   ? e0 * inv : 0.f;  gA[1] = (sm & 2)   ? e1 * inv : 0.f;
    gA[2] = (sm & 4)   ? e2 * inv : 0.f;  gA[3] = (sm & 8)   ? e3 * inv : 0.f;
    gB[0] = (sm & 16)  ? e4 * inv : 0.f;  gB[1] = (sm & 32)  ? e5 * inv : 0.f;
    gB[2] = (sm & 64)  ? e6 * inv : 0.f;  gB[3] = (sm & 128) ? e7 * inv : 0.f;

    f32x4* gp = (f32x4*)(gates + (size_t)t * NE);
    gp[0] = gA;
    gp[1] = gB;
}

// ============================================================================
// Kernel 2: MoE compute. R12 changes (occupancy/latency attack):
//  - wt_lds staging DELETED: gate scalars read per (Tp,e) from global (L2-hot).
//    LDS 43 -> 34.5 KB  => 4 blocks/CU = 16 waves/CU (was 12).
//  - all 4 x-tile B-frags packed at group start (no mid-loop global stalls).
//  - R11 per-expert eo chain (4-deep, bias rides C-init) kept.
// ============================================================================
__global__ __launch_bounds__(256, 2)
void moe_k(const float* __restrict__ x, const float* __restrict__ gates,
           const float* __restrict__ W1, const float* __restrict__ b1,
           const float* __restrict__ W2, const float* __restrict__ b2,
           float* __restrict__ out, int n_tokens)
{
    __shared__ __align__(16) s16x4 w1lds[NE * 4 * 64];   // 16 KB: [e][n][lane]
    __shared__ __align__(16) s16x4 w2lds[NE * 4 * 64];   // 16 KB: [e][q][lane]
    __shared__ __align__(16) float b1_lds[NE * HID];     // 2 KB
    __shared__ __align__(16) float b2_lds[NE * EMB];     // 512 B

    const int tid = threadIdx.x;

    // ---- per-block: weights fp32->bf16 in per-lane fragment order ----
    // w1lds[(e*4+n)*64 + lane(cg,col)][j] = W1[e][4cg+j][16n+col]   (G1 A-frag, swapped)
    // w2lds[(e*4+q)*64 + lane(cg,col)][j] = W2[e][16q+4cg+j][col]   (G2 A-frag, swapped)
    for (int s = tid; s < NE * 4 * 64; s += 256) {
        const int e = s >> 8, nq = (s >> 6) & 3, l = s & 63;
        const int cc = l & 15, gg = (l >> 4) & 3;
        const float* w1p = W1 + (e * EMB + 4 * gg) * HID + 16 * nq + cc;
        const float* w2p = W2 + (e * HID + 16 * nq + 4 * gg) * EMB + cc;
        w1lds[s] = pack_bf16x4(w1p[0], w1p[HID], w1p[2 * HID], w1p[3 * HID]);
        w2lds[s] = pack_bf16x4(w2p[0], w2p[EMB], w2p[2 * EMB], w2p[3 * EMB]);
    }
    for (int i = tid; i < NE * HID; i += 256) b1_lds[i] = b1[i];
    if (tid < NE * EMB) b2_lds[tid] = b2[tid];
    __syncthreads();

    const int lane = tid & 63;
    const int wid  = tid >> 6;
    const int col  = lane & 15;
    const int cg   = lane >> 4;

    const int n_groups = n_tokens / TPG;
    for (int g = blockIdx.x * 4 + wid; g < n_groups; g += gridDim.x * 4) {
        const int tok0 = g * TPG;

        // pack all 4 token-tile B-frags up front (x read once per group, no
        // mid-loop global-load stalls; 8 regs live)
        s16x4 xbT[4];
#pragma unroll
        for (int T = 0; T < 4; ++T) {
            const f32x4 xv = *(const f32x4*)(x + (size_t)(tok0 + 16 * T + col) * EMB + 4 * cg);
            xbT[T] = pack_bf16x4(xv[0], xv[1], xv[2], xv[3]);
        }

        // ---- two 16-token tiles per pass: weight fragments read once per 2 tiles ----
#pragma unroll 1
        for (int Tp = 0; Tp < 2; ++Tp) {
            const int tokA = tok0 + 32 * Tp + col;        // tile A
            const int tokB = tokA + 16;                    // tile B
            const s16x4 xbA = xbT[2 * Tp];
            const s16x4 xbB = xbT[2 * Tp + 1];

            f32x4 oaccA = {0.f, 0.f, 0.f, 0.f};
            f32x4 oaccB = {0.f, 0.f, 0.f, 0.f};

#pragma unroll 1
            for (int e = 0; e < NE; ++e) {
                // gate scalars straight from global (gates is 8 MB, L2-hot)
                const float wvA = gates[(size_t)tokA * NE + e];
                const float wvB = gates[(size_t)tokB * NE + e];

                // G1: h^T tile n (lane: h[tok=col][hid=16n+4cg+r]), C-in = b1.
                f32x4 hA[4], hB[4];
#pragma unroll
                for (int n = 0; n < 4; ++n) {
                    const s16x4 a1  = w1lds[(e * 4 + n) * 64 + lane];
                    const f32x4 b1c = *(const f32x4*)(b1_lds + e * HID + 16 * n + 4 * cg);
                    hA[n] = __builtin_amdgcn_mfma_f32_16x16x16bf16_1k(a1, xbA, b1c, 0, 0, 0);
                    hB[n] = __builtin_amdgcn_mfma_f32_16x16x16bf16_1k(a1, xbB, b1c, 0, 0, 0);
                }

                // G2 swapped: eo_e^T = W2^T relu(h) + b2 (C-init = b2, 4-deep chain)
                const f32x4 b2c = *(const f32x4*)(b2_lds + e * EMB + 4 * cg);
                f32x4 eoA = b2c, eoB = b2c;
#pragma unroll
                for (int q = 0; q < 4; ++q) {
                    const s16x4 a2 = w2lds[(e * 4 + q) * 64 + lane];
                    const s16x4 bA = pack_bf16x4(fmaxf(hA[q][0], 0.f), fmaxf(hA[q][1], 0.f),
                                                 fmaxf(hA[q][2], 0.f), fmaxf(hA[q][3], 0.f));
                    const s16x4 bB = pack_bf16x4(fmaxf(hB[q][0], 0.f), fmaxf(hB[q][1], 0.f),
                                                 fmaxf(hB[q][2], 0.f), fmaxf(hB[q][3], 0.f));
                    eoA = __builtin_amdgcn_mfma_f32_16x16x16bf16_1k(a2, bA, eoA, 0, 0, 0);
                    eoB = __builtin_amdgcn_mfma_f32_16x16x16bf16_1k(a2, bB, eoB, 0, 0, 0);
                }

                // weighted merge: one FMA per output element per expert
                oaccA = vfmaf(wvA, eoA, oaccA);
                oaccB = vfmaf(wvB, eoB, oaccB);
            }

            *(f32x4*)(out + (size_t)tokA * EMB + 4 * cg) = oaccA;
            *(f32x4*)(out + (size_t)tokB * EMB + 4 * cg) = oaccB;
        }
    }
}

extern "C" void kernel_launch(void* const* d_in, const int* in_sizes, int n_in,
                              void* d_out, int out_size, void* d_ws, size_t ws_size,
                              hipStream_t stream) {
    const float* x  = (const float*)d_in[0];
    const float* Wr = (const float*)d_in[1];
    const float* br = (const float*)d_in[2];
    const float* W1 = (const float*)d_in[3];
    const float* b1 = (const float*)d_in[4];
    const float* W2 = (const float*)d_in[5];
    const float* b2 = (const float*)d_in[6];
    float* out = (float*)d_out;

    const int n_tokens = in_sizes[0] / EMB;   // 262144
    float* gates = (float*)d_ws;              // 8 MB of the provided workspace

    hipLaunchKernelGGL(router_k, dim3((n_tokens + 255) / 256), dim3(256), 0, stream,
                       x, Wr, br, gates, n_tokens);
    hipLaunchKernelGGL(moe_k, dim3(1024), dim3(256), 0, stream,
                       x, gates, W1, b1, W2, b2, out, n_tokens);
}

// Round 13
// 34.776 us; speedup vs baseline: 1.1616x; 1.1616x over previous
//
#include <hip/hip_runtime.h>
#include <hip/hip_bf16.h>

#define EMB 16
#define HID 64
#define NE  8
#define TPG 64   // tokens per wave-group

typedef float  f32x4 __attribute__((ext_vector_type(4)));
typedef double f64x4 __attribute__((ext_vector_type(4)));
typedef short  s16x4 __attribute__((ext_vector_type(4)));

// fp32 -> bf16 via the standard HIP cast (RNE); compiler pairs into cvt_pk.
__device__ __forceinline__ short f2bf(float f) {
    union { __hip_bfloat16 h; short s; } u;
    u.h = __float2bfloat16(f);
    return u.s;
}
__device__ __forceinline__ s16x4 pack_bf16x4(float a, float b, float c, float d) {
    s16x4 r;
    r[0] = f2bf(a); r[1] = f2bf(b); r[2] = f2bf(c); r[3] = f2bf(d);
    return r;
}

__device__ __forceinline__ f32x4 vfmaf(float s, f32x4 a, f32x4 c) {
    f32x4 r;
    r[0] = fmaf(s, a[0], c[0]); r[1] = fmaf(s, a[1], c[1]);
    r[2] = fmaf(s, a[2], c[2]); r[3] = fmaf(s, a[3], c[3]);
    return r;
}
__device__ __forceinline__ f64x4 vfmad(double s, f32x4 a, f64x4 c) {
    f64x4 r;
    r[0] = fma(s, (double)a[0], c[0]); r[1] = fma(s, (double)a[1], c[1]);
    r[2] = fma(s, (double)a[2], c[2]); r[3] = fma(s, (double)a[3], c[3]);
    return r;
}

// ============================================================================
// Kernel 1: router (byte-identical to round 7 — proven spill-clean).
// ============================================================================
__global__ __launch_bounds__(256, 2)
void router_k(const float* __restrict__ x, const float* __restrict__ Wr,
              const float* __restrict__ br, float* __restrict__ gates,
              int n_tokens)
{
    __shared__ float wr_lds[EMB * NE];
    __shared__ float br_lds[NE];
    const int tid = threadIdx.x;
    if (tid < EMB * NE) wr_lds[tid] = Wr[tid];
    if (tid < NE) br_lds[tid] = br[tid];
    __syncthreads();

    const int t = blockIdx.x * 256 + tid;
    if (t >= n_tokens) return;

    const f32x4* xp = (const f32x4*)(x + (size_t)t * EMB);
    const f32x4 x0 = xp[0], x1 = xp[1], x2 = xp[2], x3 = xp[3];

    f32x4 lgA = *(const f32x4*)(br_lds + 0);
    f32x4 lgB = *(const f32x4*)(br_lds + 4);
#define RSTEP(K, XV) do { const float xv_ = (XV); \
        lgA = vfmaf(xv_, *(const f32x4*)(wr_lds + (K) * NE),     lgA); \
        lgB = vfmaf(xv_, *(const f32x4*)(wr_lds + (K) * NE + 4), lgB); } while (0)
    RSTEP(0,  x0[0]); RSTEP(1,  x0[1]); RSTEP(2,  x0[2]); RSTEP(3,  x0[3]);
    RSTEP(4,  x1[0]); RSTEP(5,  x1[1]); RSTEP(6,  x1[2]); RSTEP(7,  x1[3]);
    RSTEP(8,  x2[0]); RSTEP(9,  x2[1]); RSTEP(10, x2[2]); RSTEP(11, x2[3]);
    RSTEP(12, x3[0]); RSTEP(13, x3[1]); RSTEP(14, x3[2]); RSTEP(15, x3[3]);
#undef RSTEP

    float m1 = -1e30f, m2 = -1e30f, m3 = -1e30f;
#define MSCAN(V) do { const float v_ = (V); \
        const float hi_ = fmaxf(m1, v_), lo_ = fminf(m1, v_); \
        const float hi2_ = fmaxf(m2, lo_), lo2_ = fminf(m2, lo_); \
        m1 = hi_; m2 = hi2_; m3 = fmaxf(m3, lo2_); } while (0)
    MSCAN(lgA[0]); MSCAN(lgA[1]); MSCAN(lgA[2]); MSCAN(lgA[3]);
    MSCAN(lgB[0]); MSCAN(lgB[1]); MSCAN(lgB[2]); MSCAN(lgB[3]);
#undef MSCAN

    int sm = 0;
    sm |= (lgA[0] >= m2) << 0; sm |= (lgA[1] >= m2) << 1;
    sm |= (lgA[2] >= m2) << 2; sm |= (lgA[3] >= m2) << 3;
    sm |= (lgB[0] >= m2) << 4; sm |= (lgB[1] >= m2) << 5;
    sm |= (lgB[2] >= m2) << 6; sm |= (lgB[3] >= m2) << 7;

    if (__any(m2 - m3 < 1e-4f)) {
        f64x4 dA, dB;
        dA[0] = (double)br_lds[0]; dA[1] = (double)br_lds[1];
        dA[2] = (double)br_lds[2]; dA[3] = (double)br_lds[3];
        dB[0] = (double)br_lds[4]; dB[1] = (double)br_lds[5];
        dB[2] = (double)br_lds[6]; dB[3] = (double)br_lds[7];
#define DSTEP(K, XV) do { const double xv_ = (double)(XV); \
        dA = vfmad(xv_, *(const f32x4*)(wr_lds + (K) * NE),     dA); \
        dB = vfmad(xv_, *(const f32x4*)(wr_lds + (K) * NE + 4), dB); } while (0)
        DSTEP(0,  x0[0]); DSTEP(1,  x0[1]); DSTEP(2,  x0[2]); DSTEP(3,  x0[3]);
        DSTEP(4,  x1[0]); DSTEP(5,  x1[1]); DSTEP(6,  x1[2]); DSTEP(7,  x1[3]);
        DSTEP(8,  x2[0]); DSTEP(9,  x2[1]); DSTEP(10, x2[2]); DSTEP(11, x2[3]);
        DSTEP(12, x3[0]); DSTEP(13, x3[1]); DSTEP(14, x3[2]); DSTEP(15, x3[3]);
#undef DSTEP
        double M1 = -1e300, M2 = -1e300;
#define DSCAN(V) do { const double v_ = (V); \
        const double hi_ = fmax(M1, v_); M2 = fmax(M2, fmin(M1, v_)); M1 = hi_; } while (0)
        DSCAN(dA[0]); DSCAN(dA[1]); DSCAN(dA[2]); DSCAN(dA[3]);
        DSCAN(dB[0]); DSCAN(dB[1]); DSCAN(dB[2]); DSCAN(dB[3]);
#undef DSCAN
        sm = 0;
        sm |= (dA[0] >= M2) << 0; sm |= (dA[1] >= M2) << 1;
        sm |= (dA[2] >= M2) << 2; sm |= (dA[3] >= M2) << 3;
        sm |= (dB[0] >= M2) << 4; sm |= (dB[1] >= M2) << 5;
        sm |= (dB[2] >= M2) << 6; sm |= (dB[3] >= M2) << 7;
    }

    const float e0 = __expf(lgA[0] - m1), e1 = __expf(lgA[1] - m1);
    const float e2 = __expf(lgA[2] - m1), e3 = __expf(lgA[3] - m1);
    const float e4 = __expf(lgB[0] - m1), e5 = __expf(lgB[1] - m1);
    const float e6 = __expf(lgB[2] - m1), e7 = __expf(lgB[3] - m1);
    const float inv = 1.0f / (e0 + e1 + e2 + e3 + e4 + e5 + e6 + e7);
    f32x4 gA, gB;
    gA[0] = (sm & 1)   ? e0 * inv : 0.f;  gA[1] = (sm & 2)   ? e1 * inv : 0.f;
    gA[2] = (sm & 4)   ? e2 * inv : 0.f;  gA[3] = (sm & 8)   ? e3 * inv : 0.f;
    gB[0] = (sm & 16)  ? e4 * inv : 0.f;  gB[1] = (sm & 32)  ? e5 * inv : 0.f;
    gB[2] = (sm & 64)  ? e6 * inv : 0.f;  gB[3] = (sm & 128) ? e7 * inv : 0.f;

    f32x4* gp = (f32x4*)(gates + (size_t)t * NE);
    gp[0] = gA;
    gp[1] = gB;
}

// ============================================================================
// Kernel 2: MoE compute. R13: ALL FOUR 16-token tiles per expert iteration —
// a1/b1c/a2/b2c LDS fragments read once per (e, group) (per-group fragment
// traffic 155 KB -> ~80 KB; LDS BW was the dominant cost term). Gate reads
// back in the wave-private LDS slab (R12's global reads were uncoalesced).
// ============================================================================
__global__ __launch_bounds__(256, 2)
void moe_k(const float* __restrict__ x, const float* __restrict__ gates,
           const float* __restrict__ W1, const float* __restrict__ b1,
           const float* __restrict__ W2, const float* __restrict__ b2,
           float* __restrict__ out, int n_tokens)
{
    __shared__ __align__(16) s16x4 w1lds[NE * 4 * 64];   // 16 KB: [e][n][lane]
    __shared__ __align__(16) s16x4 w2lds[NE * 4 * 64];   // 16 KB: [e][q][lane]
    __shared__ __align__(16) float b1_lds[NE * HID];     // 2 KB
    __shared__ __align__(16) float b2_lds[NE * EMB];     // 512 B
    __shared__ __align__(16) float wt_lds[4 * 8 * TPG];  // 8 KB: [wave][e][tok]

    const int tid = threadIdx.x;

    // ---- per-block: weights fp32->bf16 in per-lane fragment order ----
    // w1lds[(e*4+n)*64 + lane(cg,col)][j] = W1[e][4cg+j][16n+col]   (G1 A-frag, swapped)
    // w2lds[(e*4+q)*64 + lane(cg,col)][j] = W2[e][16q+4cg+j][col]   (G2 A-frag, swapped)
    for (int s = tid; s < NE * 4 * 64; s += 256) {
        const int e = s >> 8, nq = (s >> 6) & 3, l = s & 63;
        const int cc = l & 15, gg = (l >> 4) & 3;
        const float* w1p = W1 + (e * EMB + 4 * gg) * HID + 16 * nq + cc;
        const float* w2p = W2 + (e * HID + 16 * nq + 4 * gg) * EMB + cc;
        w1lds[s] = pack_bf16x4(w1p[0], w1p[HID], w1p[2 * HID], w1p[3 * HID]);
        w2lds[s] = pack_bf16x4(w2p[0], w2p[EMB], w2p[2 * EMB], w2p[3 * EMB]);
    }
    for (int i = tid; i < NE * HID; i += 256) b1_lds[i] = b1[i];
    if (tid < NE * EMB) b2_lds[tid] = b2[tid];
    __syncthreads();

    const int lane = tid & 63;
    const int wid  = tid >> 6;
    const int col  = lane & 15;
    const int cg   = lane >> 4;
    float* wtw = wt_lds + wid * (NE * TPG);   // wave-private gate slab

    const int n_groups = n_tokens / TPG;
    for (int g = blockIdx.x * 4 + wid; g < n_groups; g += gridDim.x * 4) {
        const int tok0 = g * TPG;

        // stage this group's gates: lane loads its token's 8 gates, transposes to [e][tok]
        {
            const f32x4* gp = (const f32x4*)(gates + (size_t)(tok0 + lane) * NE);
            const f32x4 ga = gp[0], gb = gp[1];
#pragma unroll
            for (int e = 0; e < 4; ++e) wtw[e * TPG + lane] = ga[e];
#pragma unroll
            for (int e = 4; e < 8; ++e) wtw[e * TPG + lane] = gb[e - 4];
            // wave-private write->read; compiler orders via lgkmcnt, no barrier
        }

        // pack all 4 token-tile B-frags up front (x read once per group)
        s16x4 xb0, xb1, xb2, xb3;
        {
            const f32x4 v0 = *(const f32x4*)(x + (size_t)(tok0 +  0 + col) * EMB + 4 * cg);
            const f32x4 v1 = *(const f32x4*)(x + (size_t)(tok0 + 16 + col) * EMB + 4 * cg);
            const f32x4 v2 = *(const f32x4*)(x + (size_t)(tok0 + 32 + col) * EMB + 4 * cg);
            const f32x4 v3 = *(const f32x4*)(x + (size_t)(tok0 + 48 + col) * EMB + 4 * cg);
            xb0 = pack_bf16x4(v0[0], v0[1], v0[2], v0[3]);
            xb1 = pack_bf16x4(v1[0], v1[1], v1[2], v1[3]);
            xb2 = pack_bf16x4(v2[0], v2[1], v2[2], v2[3]);
            xb3 = pack_bf16x4(v3[0], v3[1], v3[2], v3[3]);
        }

        f32x4 oacc0 = {0.f,0.f,0.f,0.f}, oacc1 = {0.f,0.f,0.f,0.f};
        f32x4 oacc2 = {0.f,0.f,0.f,0.f}, oacc3 = {0.f,0.f,0.f,0.f};

#pragma unroll 1
        for (int e = 0; e < NE; ++e) {
            const float wv0 = wtw[e * TPG +  0 + col];
            const float wv1 = wtw[e * TPG + 16 + col];
            const float wv2 = wtw[e * TPG + 32 + col];
            const float wv3 = wtw[e * TPG + 48 + col];

            // G1: h^T tile n (lane: h[tok=col][hid=16n+4cg+r]), C-in = b1.
            // a1/b1c read ONCE per (e,group), feed all 4 tiles (16 indep MFMAs).
            f32x4 h0[4], h1[4], h2[4], h3[4];
#pragma unroll
            for (int n = 0; n < 4; ++n) {
                const s16x4 a1  = w1lds[(e * 4 + n) * 64 + lane];
                const f32x4 b1c = *(const f32x4*)(b1_lds + e * HID + 16 * n + 4 * cg);
                h0[n] = __builtin_amdgcn_mfma_f32_16x16x16bf16_1k(a1, xb0, b1c, 0, 0, 0);
                h1[n] = __builtin_amdgcn_mfma_f32_16x16x16bf16_1k(a1, xb1, b1c, 0, 0, 0);
                h2[n] = __builtin_amdgcn_mfma_f32_16x16x16bf16_1k(a1, xb2, b1c, 0, 0, 0);
                h3[n] = __builtin_amdgcn_mfma_f32_16x16x16bf16_1k(a1, xb3, b1c, 0, 0, 0);
            }

            // G2 swapped: eo_e^T = W2^T relu(h) + b2 (C-init = b2, 4-deep chain,
            // 4 independent chains). a2/b2c read once per (e,group).
            const f32x4 b2c = *(const f32x4*)(b2_lds + e * EMB + 4 * cg);
            f32x4 eo0 = b2c, eo1 = b2c, eo2 = b2c, eo3 = b2c;
#pragma unroll
            for (int q = 0; q < 4; ++q) {
                const s16x4 a2 = w2lds[(e * 4 + q) * 64 + lane];
                const s16x4 p0 = pack_bf16x4(fmaxf(h0[q][0], 0.f), fmaxf(h0[q][1], 0.f),
                                             fmaxf(h0[q][2], 0.f), fmaxf(h0[q][3], 0.f));
                const s16x4 p1 = pack_bf16x4(fmaxf(h1[q][0], 0.f), fmaxf(h1[q][1], 0.f),
                                             fmaxf(h1[q][2], 0.f), fmaxf(h1[q][3], 0.f));
                const s16x4 p2 = pack_bf16x4(fmaxf(h2[q][0], 0.f), fmaxf(h2[q][1], 0.f),
                                             fmaxf(h2[q][2], 0.f), fmaxf(h2[q][3], 0.f));
                const s16x4 p3 = pack_bf16x4(fmaxf(h3[q][0], 0.f), fmaxf(h3[q][1], 0.f),
                                             fmaxf(h3[q][2], 0.f), fmaxf(h3[q][3], 0.f));
                eo0 = __builtin_amdgcn_mfma_f32_16x16x16bf16_1k(a2, p0, eo0, 0, 0, 0);
                eo1 = __builtin_amdgcn_mfma_f32_16x16x16bf16_1k(a2, p1, eo1, 0, 0, 0);
                eo2 = __builtin_amdgcn_mfma_f32_16x16x16bf16_1k(a2, p2, eo2, 0, 0, 0);
                eo3 = __builtin_amdgcn_mfma_f32_16x16x16bf16_1k(a2, p3, eo3, 0, 0, 0);
            }

            // weighted merge: one FMA per output element per expert
            oacc0 = vfmaf(wv0, eo0, oacc0);
            oacc1 = vfmaf(wv1, eo1, oacc1);
            oacc2 = vfmaf(wv2, eo2, oacc2);
            oacc3 = vfmaf(wv3, eo3, oacc3);
        }

        *(f32x4*)(out + (size_t)(tok0 +  0 + col) * EMB + 4 * cg) = oacc0;
        *(f32x4*)(out + (size_t)(tok0 + 16 + col) * EMB + 4 * cg) = oacc1;
        *(f32x4*)(out + (size_t)(tok0 + 32 + col) * EMB + 4 * cg) = oacc2;
        *(f32x4*)(out + (size_t)(tok0 + 48 + col) * EMB + 4 * cg) = oacc3;
    }
}

extern "C" void kernel_launch(void* const* d_in, const int* in_sizes, int n_in,
                              void* d_out, int out_size, void* d_ws, size_t ws_size,
                              hipStream_t stream) {
    const float* x  = (const float*)d_in[0];
    const float* Wr = (const float*)d_in[1];
    const float* br = (const float*)d_in[2];
    const float* W1 = (const float*)d_in[3];
    const float* b1 = (const float*)d_in[4];
    const float* W2 = (const float*)d_in[5];
    const float* b2 = (const float*)d_in[6];
    float* out = (float*)d_out;

    const int n_tokens = in_sizes[0] / EMB;   // 262144
    float* gates = (float*)d_ws;              // 8 MB of the provided workspace

    hipLaunchKernelGGL(router_k, dim3((n_tokens + 255) / 256), dim3(256), 0, stream,
                       x, Wr, br, gates, n_tokens);
    hipLaunchKernelGGL(moe_k, dim3(1024), dim3(256), 0, stream,
                       x, gates, W1, b1, W2, b2, out, n_tokens);
}